// Round 2
// baseline (1560.625 us; speedup 1.0000x reference)
//
#include <hip/hip_runtime.h>

#define N_NODES 50000
#define N_EDGES 800000
#define C 128
#define BN_EPS 1e-5f

// Workspace layout (d_ws):
//   [0, XW_BYTES)              : xs = (x @ weight) * dinv[row]   (50000 x 128 f32)
//   [DEG_OFF, +DEG_BYTES)      : deg (then dinv)                 (50000 f32)
//   [SUM_OFF, +SUM_BYTES)      : sums[128], sumsq[128]
static constexpr size_t XW_BYTES  = (size_t)N_NODES * C * sizeof(float);   // 25,600,000
static constexpr size_t DEG_OFF   = XW_BYTES;
static constexpr size_t DEG_BYTES = (size_t)N_NODES * sizeof(float);       // 200,000
static constexpr size_t SUM_OFF   = DEG_OFF + DEG_BYTES;
static constexpr size_t SUM_BYTES = (size_t)2 * C * sizeof(float);         // 1,024

__device__ __forceinline__ void atomAddF(float* p, float v) {
    // HW global_atomic_add_f32 (plain atomicAdd(float*) may emit a CAS loop)
    unsafeAtomicAdd(p, v);
}

// ------------------------------------------------------------------- degrees
__global__ __launch_bounds__(256) void deg_kernel(const int* __restrict__ ei,
                                                  float* __restrict__ deg) {
    int e = blockIdx.x * 256 + threadIdx.x;
    if (e < N_EDGES) atomAddF(&deg[ei[N_EDGES + e]], 1.0f);  // dst row
}

__global__ __launch_bounds__(256) void dinv_kernel(float* __restrict__ deg) {
    int i = blockIdx.x * 256 + threadIdx.x;
    if (i < N_NODES) deg[i] = rsqrtf(deg[i] + 1.0f);   // D^{-1/2}, A+I degree
}

// ------------------------------------------- xs = (x @ W) * dinv[row]
// 256 threads, 32 rows/block; W staged in 32-row K-chunks.
// Xs padded to stride 132 (16B-aligned) to break the 8-way bank conflict
// that a 128-float row stride causes across ty-groups.
__global__ __launch_bounds__(256) void xw_kernel(const float* __restrict__ x,
                                                 const float* __restrict__ w,
                                                 const float* __restrict__ dinv,
                                                 float* __restrict__ xs) {
    __shared__ float Xs[32][132];  // 16.5 KB
    __shared__ float Ws[32][C];    // 16 KB (one K-chunk of W)
    const int t   = threadIdx.x;
    const int tx  = t & 31;   // col group: cols tx*4 .. tx*4+3
    const int ty  = t >> 5;   // row group: rows ty*4 .. ty*4+3
    const int row0 = blockIdx.x * 32;
    const int nrows = min(32, N_NODES - row0);

    // load X tile (guarded, float4) into padded LDS
    for (int i = t; i < 32 * (C / 4); i += 256) {
        int r = i >> 5, c4 = i & 31;
        float4 v = make_float4(0.f, 0.f, 0.f, 0.f);
        if (r < nrows)
            v = ((const float4*)(x + (size_t)(row0 + r) * C))[c4];
        ((float4*)&Xs[r][0])[c4] = v;
    }

    float4 acc[4] = {};   // acc[i] = out[row ty*4+i][cols tx*4..tx*4+3]
    for (int kt = 0; kt < C; kt += 32) {
        __syncthreads();   // protect Ws from previous chunk (and Xs on iter 0)
        for (int i = t; i < 32 * (C / 4); i += 256)
            ((float4*)&Ws[0][0])[i] = ((const float4*)(w + (size_t)kt * C))[i];
        __syncthreads();
#pragma unroll
        for (int kk4 = 0; kk4 < 8; ++kk4) {
            float4 w0 = *(const float4*)&Ws[kk4 * 4 + 0][tx * 4];
            float4 w1 = *(const float4*)&Ws[kk4 * 4 + 1][tx * 4];
            float4 w2 = *(const float4*)&Ws[kk4 * 4 + 2][tx * 4];
            float4 w3 = *(const float4*)&Ws[kk4 * 4 + 3][tx * 4];
#pragma unroll
            for (int i = 0; i < 4; ++i) {
                float4 xq = *(const float4*)&Xs[ty * 4 + i][kt + kk4 * 4];
                acc[i].x += xq.x * w0.x + xq.y * w1.x + xq.z * w2.x + xq.w * w3.x;
                acc[i].y += xq.x * w0.y + xq.y * w1.y + xq.z * w2.y + xq.w * w3.y;
                acc[i].z += xq.x * w0.z + xq.y * w1.z + xq.z * w2.z + xq.w * w3.z;
                acc[i].w += xq.x * w0.w + xq.y * w1.w + xq.z * w2.w + xq.w * w3.w;
            }
        }
    }
#pragma unroll
    for (int i = 0; i < 4; ++i) {
        int r = row0 + ty * 4 + i;
        if (r < N_NODES) {
            float dr = dinv[r];
            float4 o = make_float4(acc[i].x * dr, acc[i].y * dr,
                                   acc[i].z * dr, acc[i].w * dr);
            ((float4*)(xs + (size_t)r * C))[tx] = o;
        }
    }
}

// ------------------------------------------------------- edge scatter (atomics)
// 8 edges per 256-thread block; 32 lanes per edge, float4 per lane (128 ch).
// Pure gather + atomic add: the dinv[src]*dinv[dst] factor is folded into
// xs (src side) and the stats pass (dst side).
__global__ __launch_bounds__(256) void scatter_kernel(const int* __restrict__ ei,
                                                      const float* __restrict__ xs,
                                                      float* __restrict__ agg) {
    const int t = threadIdx.x;
    const int e = blockIdx.x * 8 + (t >> 5);
    const int l = t & 31;
    if (e >= N_EDGES) return;
    const int src = ei[e];
    const int dst = ei[N_EDGES + e];
    float4 v = ((const float4*)(xs + (size_t)src * C))[l];
    float* ap = agg + (size_t)dst * C + l * 4;
    atomAddF(ap + 0, v.x);
    atomAddF(ap + 1, v.y);
    atomAddF(ap + 2, v.z);
    atomAddF(ap + 3, v.w);
}

// ------------- self-loop + dst-scale + bias + BN partial stats (in-place on agg)
// v = (sum_src xs[src] + xs[r]) * dinv[r] + bias
#define ST_BLOCKS 200
#define ST_RPB 250
__global__ __launch_bounds__(256) void stats_kernel(const float* __restrict__ xs,
                                                    const float* __restrict__ dinv,
                                                    const float* __restrict__ bias,
                                                    float* __restrict__ agg,
                                                    float* __restrict__ sums) {
    const int t  = threadIdx.x;
    const int cg = t & 31;   // float4 column group
    const int rg = t >> 5;   // 0..7
    const float4 b = ((const float4*)bias)[cg];
    float sx = 0.f, sy = 0.f, sz = 0.f, sw = 0.f;
    float qx = 0.f, qy = 0.f, qz = 0.f, qw = 0.f;
    const int rend = min(N_NODES, (blockIdx.x + 1) * ST_RPB);
    for (int r = blockIdx.x * ST_RPB + rg; r < rend; r += 8) {
        float di = dinv[r];
        float4 a  = ((float4*)(agg + (size_t)r * C))[cg];
        float4 xv = ((const float4*)(xs + (size_t)r * C))[cg];
        float4 v;
        v.x = (a.x + xv.x) * di + b.x;
        v.y = (a.y + xv.y) * di + b.y;
        v.z = (a.z + xv.z) * di + b.z;
        v.w = (a.w + xv.w) * di + b.w;
        ((float4*)(agg + (size_t)r * C))[cg] = v;
        sx += v.x; sy += v.y; sz += v.z; sw += v.w;
        qx += v.x * v.x; qy += v.y * v.y; qz += v.z * v.z; qw += v.w * v.w;
    }
    __shared__ float4 lss[8][32];
    __shared__ float4 lqq[8][32];
    lss[rg][cg] = make_float4(sx, sy, sz, sw);
    lqq[rg][cg] = make_float4(qx, qy, qz, qw);
    __syncthreads();
    if (rg == 0) {
        float4 S = lss[0][cg], Q = lqq[0][cg];
#pragma unroll
        for (int i = 1; i < 8; ++i) {
            float4 a = lss[i][cg], c = lqq[i][cg];
            S.x += a.x; S.y += a.y; S.z += a.z; S.w += a.w;
            Q.x += c.x; Q.y += c.y; Q.z += c.z; Q.w += c.w;
        }
        atomAddF(&sums[cg * 4 + 0], S.x);
        atomAddF(&sums[cg * 4 + 1], S.y);
        atomAddF(&sums[cg * 4 + 2], S.z);
        atomAddF(&sums[cg * 4 + 3], S.w);
        atomAddF(&sums[C + cg * 4 + 0], Q.x);
        atomAddF(&sums[C + cg * 4 + 1], Q.y);
        atomAddF(&sums[C + cg * 4 + 2], Q.z);
        atomAddF(&sums[C + cg * 4 + 3], Q.w);
    }
}

// --------------------------------------------------- BN normalize + ReLU (in place)
__global__ __launch_bounds__(256) void finalize_kernel(const float* __restrict__ sums,
                                                       const float* __restrict__ gamma,
                                                       const float* __restrict__ beta,
                                                       float* __restrict__ out) {
    __shared__ float sc[C];
    __shared__ float sh[C];
    const int t = threadIdx.x;
    if (t < C) {
        const float invN = 1.0f / (float)N_NODES;
        float m   = sums[t] * invN;
        float var = fmaxf(sums[C + t] * invN - m * m, 0.0f);
        float s   = gamma[t] * rsqrtf(var + BN_EPS);
        sc[t] = s;
        sh[t] = beta[t] - m * s;
    }
    __syncthreads();
    size_t i = (size_t)blockIdx.x * 256 + t;   // float4 index
    int c4 = (i & 31) * 4;
    float4 v = ((const float4*)out)[i];
    v.x = fmaxf(v.x * sc[c4 + 0] + sh[c4 + 0], 0.f);
    v.y = fmaxf(v.y * sc[c4 + 1] + sh[c4 + 1], 0.f);
    v.z = fmaxf(v.z * sc[c4 + 2] + sh[c4 + 2], 0.f);
    v.w = fmaxf(v.w * sc[c4 + 3] + sh[c4 + 3], 0.f);
    ((float4*)out)[i] = v;
}

extern "C" void kernel_launch(void* const* d_in, const int* in_sizes, int n_in,
                              void* d_out, int out_size, void* d_ws, size_t ws_size,
                              hipStream_t stream) {
    const float* x      = (const float*)d_in[0];
    const int*   ei     = (const int*)d_in[1];   // [2][N_EDGES], int32
    const float* weight = (const float*)d_in[2];
    const float* bias   = (const float*)d_in[3];
    const float* gamma  = (const float*)d_in[4];
    const float* beta   = (const float*)d_in[5];

    float* xs   = (float*)d_ws;
    float* deg  = (float*)((char*)d_ws + DEG_OFF);   // becomes dinv
    float* sums = (float*)((char*)d_ws + SUM_OFF);
    float* agg  = (float*)d_out;                     // aggregate in-place in d_out

    // zero: agg (scatter target), deg, sums  (ws/out are poisoned 0xAA each call)
    hipMemsetAsync(d_out, 0, XW_BYTES, stream);
    hipMemsetAsync((char*)d_ws + DEG_OFF, 0, DEG_BYTES + SUM_BYTES, stream);

    // 1) degree count (dst) then dinv = rsqrt(deg+1)  — needed before xw scaling
    deg_kernel<<<(N_EDGES + 255) / 256, 256, 0, stream>>>(ei, deg);
    dinv_kernel<<<(N_NODES + 255) / 256, 256, 0, stream>>>(deg);
    // 2) xs = (x @ W) * dinv[row]
    xw_kernel<<<(N_NODES + 31) / 32, 256, 0, stream>>>(x, weight, deg, xs);
    // 3) edge scatter-add with atomics (pure gather+add)
    scatter_kernel<<<(N_EDGES + 7) / 8, 256, 0, stream>>>(ei, xs, agg);
    // 4) self-loop + dst scale + bias + BN stats
    stats_kernel<<<ST_BLOCKS, 256, 0, stream>>>(xs, deg, bias, agg, sums);
    // 5) BN normalize + ReLU
    finalize_kernel<<<(N_NODES * (C / 4)) / 256, 256, 0, stream>>>(sums, gamma, beta, (float*)d_out);
}

// Round 3
// 419.237 us; speedup vs baseline: 3.7225x; 3.7225x over previous
//
#include <hip/hip_runtime.h>

#define N_NODES 50000
#define N_EDGES 800000
#define C 128
#define BN_EPS 1e-5f
#define GB 1024   // gather grid blocks

// ---- workspace layout (aligned to 256B) ----
static constexpr size_t alignup(size_t v) { return (v + 255) & ~(size_t)255; }
static constexpr size_t XS_OFF   = 0;
static constexpr size_t XS_BYTES = (size_t)N_NODES * C * sizeof(float);      // 25.6 MB
static constexpr size_t DEG_OFF  = alignup(XS_OFF + XS_BYTES);               // int deg -> float dinv (in place)
static constexpr size_t DEG_BYTES= (size_t)N_NODES * sizeof(int);
static constexpr size_t ROW_OFF  = alignup(DEG_OFF + DEG_BYTES);             // rowstart[int x N_NODES]
static constexpr size_t ROW_BYTES= (size_t)N_NODES * sizeof(int);
static constexpr size_t SRC_OFF  = alignup(ROW_OFF + ROW_BYTES);             // srcs_sorted[int x N_EDGES]
static constexpr size_t SRC_BYTES= (size_t)N_EDGES * sizeof(int);
static constexpr size_t SUM_OFF  = alignup(SRC_OFF + SRC_BYTES);             // sums[128] + sumsq[128]
static constexpr size_t SUM_BYTES= (size_t)2 * C * sizeof(float);

__device__ __forceinline__ void atomAddF(float* p, float v) { unsafeAtomicAdd(p, v); }

// ------------------------------------------------------------- degree histogram
__global__ __launch_bounds__(256) void deg_kernel(const int* __restrict__ ei,
                                                  int* __restrict__ degi) {
    int e = blockIdx.x * 256 + threadIdx.x;
    if (e < N_EDGES) atomicAdd(&degi[ei[N_EDGES + e]], 1);   // dst row
}

// --------------------------------------------- exclusive prefix scan (1 block)
__global__ __launch_bounds__(1024) void scan_kernel(const int* __restrict__ degi,
                                                    int* __restrict__ rowstart) {
    const int t = threadIdx.x;
    const int CHUNK = (N_NODES + 1023) / 1024;   // 49
    const int base = t * CHUNK;
    int lsum = 0;
    for (int i = 0; i < CHUNK; ++i) {
        int idx = base + i;
        if (idx < N_NODES) lsum += degi[idx];
    }
    __shared__ int ps[1024];
    ps[t] = lsum;
    __syncthreads();
    for (int off = 1; off < 1024; off <<= 1) {
        int v = (t >= off) ? ps[t - off] : 0;
        __syncthreads();
        ps[t] += v;
        __syncthreads();
    }
    int run = ps[t] - lsum;   // exclusive prefix of this thread's chunk
    for (int i = 0; i < CHUNK; ++i) {
        int idx = base + i;
        if (idx < N_NODES) { rowstart[idx] = run; run += degi[idx]; }
    }
}

// ------------------------------------- dinv = rsqrt(deg+1), in place over degi
__global__ __launch_bounds__(256) void dinv_kernel(const int* __restrict__ degi,
                                                   float* __restrict__ dinv) {
    int i = blockIdx.x * 256 + threadIdx.x;
    if (i < N_NODES) {
        int d = degi[i];
        dinv[i] = rsqrtf((float)d + 1.0f);
    }
}

// -------------------- fill: place src of each edge into dst-sorted position.
// rowstart is consumed as cursors; post-fill rowstart[d] == original rowstart[d+1].
__global__ __launch_bounds__(256) void fill_kernel(const int* __restrict__ ei,
                                                   int* __restrict__ rowstart,
                                                   int* __restrict__ srcs) {
    int e = blockIdx.x * 256 + threadIdx.x;
    if (e < N_EDGES) {
        int dst = ei[N_EDGES + e];
        int pos = atomicAdd(&rowstart[dst], 1);
        srcs[pos] = ei[e];
    }
}

// ------------------------------------------- xs = (x @ W) * dinv[row]
// 256 threads, 32 rows/block; W staged in 32-row K-chunks; Xs padded (132).
__global__ __launch_bounds__(256) void xw_kernel(const float* __restrict__ x,
                                                 const float* __restrict__ w,
                                                 const float* __restrict__ dinv,
                                                 float* __restrict__ xs) {
    __shared__ float Xs[32][132];
    __shared__ float Ws[32][C];
    const int t   = threadIdx.x;
    const int tx  = t & 31;
    const int ty  = t >> 5;
    const int row0 = blockIdx.x * 32;
    const int nrows = min(32, N_NODES - row0);

    for (int i = t; i < 32 * (C / 4); i += 256) {
        int r = i >> 5, c4 = i & 31;
        float4 v = make_float4(0.f, 0.f, 0.f, 0.f);
        if (r < nrows)
            v = ((const float4*)(x + (size_t)(row0 + r) * C))[c4];
        ((float4*)&Xs[r][0])[c4] = v;
    }

    float4 acc[4] = {};
    for (int kt = 0; kt < C; kt += 32) {
        __syncthreads();
        for (int i = t; i < 32 * (C / 4); i += 256)
            ((float4*)&Ws[0][0])[i] = ((const float4*)(w + (size_t)kt * C))[i];
        __syncthreads();
#pragma unroll
        for (int kk4 = 0; kk4 < 8; ++kk4) {
            float4 w0 = *(const float4*)&Ws[kk4 * 4 + 0][tx * 4];
            float4 w1 = *(const float4*)&Ws[kk4 * 4 + 1][tx * 4];
            float4 w2 = *(const float4*)&Ws[kk4 * 4 + 2][tx * 4];
            float4 w3 = *(const float4*)&Ws[kk4 * 4 + 3][tx * 4];
#pragma unroll
            for (int i = 0; i < 4; ++i) {
                float4 xq = *(const float4*)&Xs[ty * 4 + i][kt + kk4 * 4];
                acc[i].x += xq.x * w0.x + xq.y * w1.x + xq.z * w2.x + xq.w * w3.x;
                acc[i].y += xq.x * w0.y + xq.y * w1.y + xq.z * w2.y + xq.w * w3.y;
                acc[i].z += xq.x * w0.z + xq.y * w1.z + xq.z * w2.z + xq.w * w3.z;
                acc[i].w += xq.x * w0.w + xq.y * w1.w + xq.z * w2.w + xq.w * w3.w;
            }
        }
    }
#pragma unroll
    for (int i = 0; i < 4; ++i) {
        int r = row0 + ty * 4 + i;
        if (r < N_NODES) {
            float dr = dinv[r];
            ((float4*)(xs + (size_t)r * C))[tx] =
                make_float4(acc[i].x * dr, acc[i].y * dr, acc[i].z * dr, acc[i].w * dr);
        }
    }
}

// -------- gather: per-dst segmented reduction + self-loop + scale + bias + BN partials
// One 64-lane wave per dst row (grid-stride). Lane owns channels 2*lane, 2*lane+1.
__global__ __launch_bounds__(256) void gather_kernel(const int* __restrict__ srcs,
                                                     const int* __restrict__ rowstart,
                                                     const float* __restrict__ xs,
                                                     const float* __restrict__ dinv,
                                                     const float* __restrict__ bias,
                                                     float* __restrict__ out,
                                                     float* __restrict__ sums) {
    const int t    = threadIdx.x;
    const int lane = t & 63;
    const int wv   = t >> 6;                   // 4 waves/block
    const float2 bia = ((const float2*)bias)[lane];
    float sx = 0.f, sy = 0.f, qx = 0.f, qy = 0.f;

    for (int d0 = blockIdx.x * 4 + wv; d0 < N_NODES; d0 += GB * 4) {
        const int d  = __builtin_amdgcn_readfirstlane(d0);
        const int r0 = __builtin_amdgcn_readfirstlane(d ? rowstart[d - 1] : 0);
        const int r1 = __builtin_amdgcn_readfirstlane(rowstart[d]);
        float2 acc = ((const float2*)(xs + (size_t)d * C))[lane];   // self-loop term
        int p = r0;
        for (; p + 4 <= r1; p += 4) {
            int s0 = srcs[p], s1 = srcs[p + 1], s2 = srcs[p + 2], s3 = srcs[p + 3];
            float2 a0 = ((const float2*)(xs + (size_t)s0 * C))[lane];
            float2 a1 = ((const float2*)(xs + (size_t)s1 * C))[lane];
            float2 a2 = ((const float2*)(xs + (size_t)s2 * C))[lane];
            float2 a3 = ((const float2*)(xs + (size_t)s3 * C))[lane];
            acc.x += (a0.x + a1.x) + (a2.x + a3.x);
            acc.y += (a0.y + a1.y) + (a2.y + a3.y);
        }
        for (; p < r1; ++p) {
            int s = srcs[p];
            float2 a = ((const float2*)(xs + (size_t)s * C))[lane];
            acc.x += a.x; acc.y += a.y;
        }
        const float di = dinv[d];
        float2 v = make_float2(acc.x * di + bia.x, acc.y * di + bia.y);
        ((float2*)(out + (size_t)d * C))[lane] = v;
        sx += v.x; sy += v.y;
        qx += v.x * v.x; qy += v.y * v.y;
    }

    // block-level BN partial reduce: channel c owned by lane c/2 of every wave
    __shared__ float2 rs[256];
    __shared__ float2 rq[256];
    rs[t] = make_float2(sx, sy);
    rq[t] = make_float2(qx, qy);
    __syncthreads();
    if (t < 64) {
        float2 S = rs[t], Q = rq[t];
#pragma unroll
        for (int i = 1; i < 4; ++i) {
            S.x += rs[t + 64 * i].x; S.y += rs[t + 64 * i].y;
            Q.x += rq[t + 64 * i].x; Q.y += rq[t + 64 * i].y;
        }
        atomAddF(&sums[2 * t + 0], S.x);
        atomAddF(&sums[2 * t + 1], S.y);
        atomAddF(&sums[C + 2 * t + 0], Q.x);
        atomAddF(&sums[C + 2 * t + 1], Q.y);
    }
}

// --------------------------------------------------- BN normalize + ReLU (in place)
__global__ __launch_bounds__(256) void finalize_kernel(const float* __restrict__ sums,
                                                       const float* __restrict__ gamma,
                                                       const float* __restrict__ beta,
                                                       float* __restrict__ out) {
    __shared__ float sc[C];
    __shared__ float sh[C];
    const int t = threadIdx.x;
    if (t < C) {
        const float invN = 1.0f / (float)N_NODES;
        float m   = sums[t] * invN;
        float var = fmaxf(sums[C + t] * invN - m * m, 0.0f);
        float s   = gamma[t] * rsqrtf(var + BN_EPS);
        sc[t] = s;
        sh[t] = beta[t] - m * s;
    }
    __syncthreads();
    size_t i = (size_t)blockIdx.x * 256 + t;   // float4 index
    int c4 = (i & 31) * 4;
    float4 v = ((const float4*)out)[i];
    v.x = fmaxf(v.x * sc[c4 + 0] + sh[c4 + 0], 0.f);
    v.y = fmaxf(v.y * sc[c4 + 1] + sh[c4 + 1], 0.f);
    v.z = fmaxf(v.z * sc[c4 + 2] + sh[c4 + 2], 0.f);
    v.w = fmaxf(v.w * sc[c4 + 3] + sh[c4 + 3], 0.f);
    ((float4*)out)[i] = v;
}

extern "C" void kernel_launch(void* const* d_in, const int* in_sizes, int n_in,
                              void* d_out, int out_size, void* d_ws, size_t ws_size,
                              hipStream_t stream) {
    const float* x      = (const float*)d_in[0];
    const int*   ei     = (const int*)d_in[1];   // [2][N_EDGES]
    const float* weight = (const float*)d_in[2];
    const float* bias   = (const float*)d_in[3];
    const float* gamma  = (const float*)d_in[4];
    const float* beta   = (const float*)d_in[5];

    float* xs       = (float*)((char*)d_ws + XS_OFF);
    int*   degi     = (int*)  ((char*)d_ws + DEG_OFF);
    float* dinv     = (float*)((char*)d_ws + DEG_OFF);   // overwrites degi after scan
    int*   rowstart = (int*)  ((char*)d_ws + ROW_OFF);
    int*   srcs     = (int*)  ((char*)d_ws + SRC_OFF);
    float* sums     = (float*)((char*)d_ws + SUM_OFF);

    // zero only what needs it: degi histogram + BN sums
    hipMemsetAsync((char*)d_ws + DEG_OFF, 0, DEG_BYTES, stream);
    hipMemsetAsync((char*)d_ws + SUM_OFF, 0, SUM_BYTES, stream);

    // 1) dst-degree histogram (int atomics)
    deg_kernel<<<(N_EDGES + 255) / 256, 256, 0, stream>>>(ei, degi);
    // 2) exclusive scan -> rowstart  (reads degi; must precede dinv overwrite)
    scan_kernel<<<1, 1024, 0, stream>>>(degi, rowstart);
    // 3) dinv = rsqrt(deg+1), in place
    dinv_kernel<<<(N_NODES + 255) / 256, 256, 0, stream>>>(degi, dinv);
    // 4) CSR fill: srcs sorted by dst (rowstart becomes row-end cursors)
    fill_kernel<<<(N_EDGES + 255) / 256, 256, 0, stream>>>(ei, rowstart, srcs);
    // 5) xs = (x @ W) * dinv[row]
    xw_kernel<<<(N_NODES + 31) / 32, 256, 0, stream>>>(x, weight, dinv, xs);
    // 6) segmented gather-reduce + self-loop + scale + bias + BN partials -> out
    gather_kernel<<<GB, 256, 0, stream>>>(srcs, rowstart, xs, dinv, bias,
                                          (float*)d_out, sums);
    // 7) BN normalize + ReLU
    finalize_kernel<<<(N_NODES * (C / 4)) / 256, 256, 0, stream>>>(sums, gamma, beta,
                                                                   (float*)d_out);
}

// Round 10
// 355.504 us; speedup vs baseline: 4.3899x; 1.1793x over previous
//
#include <hip/hip_runtime.h>

#define N_NODES 50000
#define N_EDGES 800000
#define C 128
#define BN_EPS 1e-5f
#define GB 2048   // gather grid blocks: 2048*4 waves = 8192 = full wave-slot fill
#define SCB 196   // scan blocks: 196*256 = 50176 >= N_NODES

// ---- workspace layout (aligned to 256B) ----
static constexpr size_t alignup(size_t v) { return (v + 255) & ~(size_t)255; }
static constexpr size_t XS_OFF   = 0;
static constexpr size_t XS_BYTES = (size_t)N_NODES * C * sizeof(float);      // 25.6 MB
static constexpr size_t DEG_OFF  = alignup(XS_OFF + XS_BYTES);               // int deg -> float dinv (in place)
static constexpr size_t DEG_BYTES= (size_t)N_NODES * sizeof(int);
static constexpr size_t ROW_OFF  = alignup(DEG_OFF + DEG_BYTES);             // rowstart[int x N_NODES]
static constexpr size_t ROW_BYTES= (size_t)N_NODES * sizeof(int);
static constexpr size_t SRC_OFF  = alignup(ROW_OFF + ROW_BYTES);             // srcs_sorted[int x N_EDGES]
static constexpr size_t SRC_BYTES= (size_t)N_EDGES * sizeof(int);
static constexpr size_t SUM_OFF  = alignup(SRC_OFF + SRC_BYTES);             // sums[128]+sumsq[128]
static constexpr size_t SUM_BYTES= (size_t)2 * C * sizeof(float);
static constexpr size_t BS_OFF   = alignup(SUM_OFF + SUM_BYTES);             // bsum[SCB], boff[SCB]
static constexpr size_t BS_BYTES = (size_t)2 * SCB * sizeof(int);
static constexpr size_t WT_OFF   = alignup(BS_OFF + BS_BYTES);               // wt_hi, wt_lo (bf16 128x128 each)
static constexpr size_t WT_BYTES = (size_t)2 * C * C * sizeof(short);

using frag_ab = __attribute__((ext_vector_type(8))) short;  // 8 bf16 (4 VGPRs)
using f32x4   = __attribute__((ext_vector_type(4))) float;

__device__ __forceinline__ void atomAddF(float* p, float v) { unsafeAtomicAdd(p, v); }

__device__ __forceinline__ unsigned short f2bf(float f) {   // RNE float->bf16 bits
    unsigned u = __float_as_uint(f);
    return (unsigned short)((u + 0x7fffu + ((u >> 16) & 1u)) >> 16);
}
__device__ __forceinline__ float bf2f(unsigned short h) {
    return __uint_as_float(((unsigned)h) << 16);
}

// ------------------------------------------------------------- degree histogram
__global__ __launch_bounds__(256) void deg_kernel(const int* __restrict__ ei,
                                                  int* __restrict__ degi) {
    int e = blockIdx.x * 256 + threadIdx.x;
    if (e < N_EDGES) atomicAdd(&degi[ei[N_EDGES + e]], 1);   // dst row
}

// ------------------------------------------------- 3-phase exclusive scan of degi
__global__ __launch_bounds__(256) void scanA_kernel(const int* __restrict__ degi,
                                                    int* __restrict__ bsum) {
    const int t = threadIdx.x, b = blockIdx.x;
    int i = b * 256 + t;
    int v = (i < N_NODES) ? degi[i] : 0;
    __shared__ int ps[256];
    ps[t] = v; __syncthreads();
    for (int s = 128; s > 0; s >>= 1) { if (t < s) ps[t] += ps[t + s]; __syncthreads(); }
    if (t == 0) bsum[b] = ps[0];
}
__global__ __launch_bounds__(256) void scanB_kernel(const int* __restrict__ bsum,
                                                    int* __restrict__ boff) {
    const int t = threadIdx.x;
    int v = (t < SCB) ? bsum[t] : 0;
    __shared__ int ps[256];
    ps[t] = v; __syncthreads();
    for (int off = 1; off < 256; off <<= 1) {
        int u = (t >= off) ? ps[t - off] : 0;
        __syncthreads(); ps[t] += u; __syncthreads();
    }
    if (t < SCB) boff[t] = ps[t] - v;   // exclusive
}
__global__ __launch_bounds__(256) void scanC_kernel(const int* __restrict__ degi,
                                                    const int* __restrict__ boff,
                                                    int* __restrict__ rowstart) {
    const int t = threadIdx.x, b = blockIdx.x;
    int i = b * 256 + t;
    int v = (i < N_NODES) ? degi[i] : 0;
    __shared__ int ps[256];
    ps[t] = v; __syncthreads();
    for (int off = 1; off < 256; off <<= 1) {
        int u = (t >= off) ? ps[t - off] : 0;
        __syncthreads(); ps[t] += u; __syncthreads();
    }
    if (i < N_NODES) rowstart[i] = boff[b] + ps[t] - v;   // exclusive start
}

// ------------------------------------- dinv = rsqrt(deg+1), in place over degi
__global__ __launch_bounds__(256) void dinv_kernel(const int* __restrict__ degi,
                                                   float* __restrict__ dinv) {
    int i = blockIdx.x * 256 + threadIdx.x;
    if (i < N_NODES) dinv[i] = rsqrtf((float)degi[i] + 1.0f);
}

// -------------------- fill: place src of each edge into dst-sorted position.
// rowstart is consumed as cursors; post-fill rowstart[d] == original rowstart[d+1].
__global__ __launch_bounds__(256) void fill_kernel(const int* __restrict__ ei,
                                                   int* __restrict__ rowstart,
                                                   int* __restrict__ srcs) {
    int e = blockIdx.x * 256 + threadIdx.x;
    if (e < N_EDGES) {
        int dst = ei[N_EDGES + e];
        int pos = atomicAdd(&rowstart[dst], 1);
        srcs[pos] = ei[e];
    }
}

// ---------------- W -> W^T, split to bf16 hi/lo (done once per call; 16K elems)
__global__ __launch_bounds__(256) void wconv_kernel(const float* __restrict__ w,
                                                    unsigned short* __restrict__ wt_hi,
                                                    unsigned short* __restrict__ wt_lo) {
    int idx = blockIdx.x * 256 + threadIdx.x;   // 64 blocks * 256 = 16384
    int k = idx >> 7, n = idx & 127;
    float v = w[idx];
    unsigned short h = f2bf(v);
    wt_hi[n * C + k] = h;
    wt_lo[n * C + k] = f2bf(v - bf2f(h));
}

// --------------------- xs = (x @ W) * dinv[row]  via bf16 hi/lo split MFMA
// Block: 256 thr (4 waves), BM=64 rows, N=128, K chunked by 64.
// mfma_f32_16x16x32_bf16: A lane: row=lane&15, k=(lane>>4)*8+j;
//                         B lane: col=lane&15, k=(lane>>4)*8+j  (stage W^T);
//                         D lane: col=lane&15, row=(lane>>4)*4+reg  [m89-verified].
__global__ __launch_bounds__(256) void xw_mfma_kernel(const float* __restrict__ x,
                                                      const unsigned short* __restrict__ wt_hi,
                                                      const unsigned short* __restrict__ wt_lo,
                                                      const float* __restrict__ dinv,
                                                      float* __restrict__ xs) {
    __shared__ unsigned short Ah[64][72], Al[64][72];    // 9216 B each
    __shared__ unsigned short Bh[128][72], Bl[128][72];  // 18432 B each; total 55.3 KB
    const int t    = threadIdx.x;
    const int wv   = t >> 6;
    const int lane = t & 63;
    const int lr   = lane & 15;       // frag row/col
    const int kg   = lane >> 4;       // k-group (0..3)
    const int row0 = blockIdx.x * 64;

    f32x4 acc[8] = {};   // 8 n-tiles of 16, rows wv*16..wv*16+15

    for (int kt = 0; kt < C; kt += 64) {
        __syncthreads();   // protect LDS from previous chunk's readers
        // stage A: rows 0..63, k = kt..kt+63. thread: r = t>>2, 16-k chunk c16 = t&3
        {
            const int r = t >> 2, c16 = t & 3;
            const int gr = row0 + r;
            const float* xp = x + (size_t)gr * C + kt + c16 * 16;
#pragma unroll
            for (int q = 0; q < 4; ++q) {
                float4 v = make_float4(0.f, 0.f, 0.f, 0.f);
                if (gr < N_NODES) v = *(const float4*)(xp + q * 4);
                unsigned short h0 = f2bf(v.x), h1 = f2bf(v.y), h2 = f2bf(v.z), h3 = f2bf(v.w);
                ushort4 hv = make_ushort4(h0, h1, h2, h3);
                ushort4 lv = make_ushort4(f2bf(v.x - bf2f(h0)), f2bf(v.y - bf2f(h1)),
                                          f2bf(v.z - bf2f(h2)), f2bf(v.w - bf2f(h3)));
                *(ushort4*)&Ah[r][c16 * 16 + q * 4] = hv;
                *(ushort4*)&Al[r][c16 * 16 + q * 4] = lv;
            }
        }
        // stage B: n = t>>1 (0..127), half = t&1 -> 32 k values
        {
            const int n = t >> 1, half = t & 1;
            const unsigned short* ph = wt_hi + (size_t)n * C + kt + half * 32;
            const unsigned short* pl = wt_lo + (size_t)n * C + kt + half * 32;
#pragma unroll
            for (int q = 0; q < 4; ++q) {
                *(int4*)&Bh[n][half * 32 + q * 8] = *(const int4*)(ph + q * 8);
                *(int4*)&Bl[n][half * 32 + q * 8] = *(const int4*)(pl + q * 8);
            }
        }
        __syncthreads();
#pragma unroll
        for (int ks = 0; ks < 2; ++ks) {
            frag_ab a_h = *(const frag_ab*)&Ah[wv * 16 + lr][ks * 32 + kg * 8];
            frag_ab a_l = *(const frag_ab*)&Al[wv * 16 + lr][ks * 32 + kg * 8];
#pragma unroll
            for (int nt = 0; nt < 8; ++nt) {
                frag_ab b_h = *(const frag_ab*)&Bh[nt * 16 + lr][ks * 32 + kg * 8];
                frag_ab b_l = *(const frag_ab*)&Bl[nt * 16 + lr][ks * 32 + kg * 8];
                acc[nt] = __builtin_amdgcn_mfma_f32_16x16x32_bf16(a_h, b_h, acc[nt], 0, 0, 0);
                acc[nt] = __builtin_amdgcn_mfma_f32_16x16x32_bf16(a_l, b_h, acc[nt], 0, 0, 0);
                acc[nt] = __builtin_amdgcn_mfma_f32_16x16x32_bf16(a_h, b_l, acc[nt], 0, 0, 0);
            }
        }
    }

    // epilogue: D row = (lane>>4)*4 + r, col = lane&15
    float dv[4]; int gm[4];
#pragma unroll
    for (int r = 0; r < 4; ++r) {
        gm[r] = row0 + wv * 16 + kg * 4 + r;
        dv[r] = (gm[r] < N_NODES) ? dinv[gm[r]] : 0.f;
    }
#pragma unroll
    for (int nt = 0; nt < 8; ++nt)
#pragma unroll
        for (int r = 0; r < 4; ++r)
            if (gm[r] < N_NODES)
                xs[(size_t)gm[r] * C + nt * 16 + lr] = acc[nt][r] * dv[r];
}

// -------- gather: per-dst segmented reduction + self-loop + scale + bias + BN partials
// One 64-lane wave per dst row (grid-stride). Lane owns channels 2*lane, 2*lane+1.
__global__ __launch_bounds__(256) void gather_kernel(const int* __restrict__ srcs,
                                                     const int* __restrict__ rowstart,
                                                     const float* __restrict__ xs,
                                                     const float* __restrict__ dinv,
                                                     const float* __restrict__ bias,
                                                     float* __restrict__ out,
                                                     float* __restrict__ sums) {
    const int t    = threadIdx.x;
    const int lane = t & 63;
    const int wv   = t >> 6;                   // 4 waves/block
    const float2 bia = ((const float2*)bias)[lane];
    float sx = 0.f, sy = 0.f, qx = 0.f, qy = 0.f;

    for (int d0 = blockIdx.x * 4 + wv; d0 < N_NODES; d0 += GB * 4) {
        const int d  = __builtin_amdgcn_readfirstlane(d0);
        const int r0 = __builtin_amdgcn_readfirstlane(d ? rowstart[d - 1] : 0);
        const int r1 = __builtin_amdgcn_readfirstlane(rowstart[d]);
        float2 acc = ((const float2*)(xs + (size_t)d * C))[lane];   // self-loop term
        int p = r0;
        if (p + 4 <= r1) {
            int i0 = srcs[p], i1 = srcs[p + 1], i2 = srcs[p + 2], i3 = srcs[p + 3];
            for (;;) {
                const int q = p + 4;
                const bool more = (q + 4 <= r1);
                int j0, j1, j2, j3;
                if (more) { j0 = srcs[q]; j1 = srcs[q + 1]; j2 = srcs[q + 2]; j3 = srcs[q + 3]; }
                float2 a0 = ((const float2*)(xs + (size_t)i0 * C))[lane];
                float2 a1 = ((const float2*)(xs + (size_t)i1 * C))[lane];
                float2 a2 = ((const float2*)(xs + (size_t)i2 * C))[lane];
                float2 a3 = ((const float2*)(xs + (size_t)i3 * C))[lane];
                acc.x += (a0.x + a1.x) + (a2.x + a3.x);
                acc.y += (a0.y + a1.y) + (a2.y + a3.y);
                p = q;
                if (!more) break;
                i0 = j0; i1 = j1; i2 = j2; i3 = j3;
            }
        }
        for (; p < r1; ++p) {
            float2 a = ((const float2*)(xs + (size_t)srcs[p] * C))[lane];
            acc.x += a.x; acc.y += a.y;
        }
        const float di = dinv[d];
        float2 v = make_float2(acc.x * di + bia.x, acc.y * di + bia.y);
        ((float2*)(out + (size_t)d * C))[lane] = v;
        sx += v.x; sy += v.y;
        qx += v.x * v.x; qy += v.y * v.y;
    }

    __shared__ float2 rs[256];
    __shared__ float2 rq[256];
    rs[t] = make_float2(sx, sy);
    rq[t] = make_float2(qx, qy);
    __syncthreads();
    if (t < 64) {
        float2 S = rs[t], Q = rq[t];
#pragma unroll
        for (int i = 1; i < 4; ++i) {
            S.x += rs[t + 64 * i].x; S.y += rs[t + 64 * i].y;
            Q.x += rq[t + 64 * i].x; Q.y += rq[t + 64 * i].y;
        }
        atomAddF(&sums[2 * t + 0], S.x);
        atomAddF(&sums[2 * t + 1], S.y);
        atomAddF(&sums[C + 2 * t + 0], Q.x);
        atomAddF(&sums[C + 2 * t + 1], Q.y);
    }
}

// --------------------------------------------------- BN normalize + ReLU (in place)
__global__ __launch_bounds__(256) void finalize_kernel(const float* __restrict__ sums,
                                                       const float* __restrict__ gamma,
                                                       const float* __restrict__ beta,
                                                       float* __restrict__ out) {
    __shared__ float sc[C];
    __shared__ float sh[C];
    const int t = threadIdx.x;
    if (t < C) {
        const float invN = 1.0f / (float)N_NODES;
        float m   = sums[t] * invN;
        float var = fmaxf(sums[C + t] * invN - m * m, 0.0f);
        float s   = gamma[t] * rsqrtf(var + BN_EPS);
        sc[t] = s;
        sh[t] = beta[t] - m * s;
    }
    __syncthreads();
    size_t i = (size_t)blockIdx.x * 256 + t;   // float4 index
    int c4 = (i & 31) * 4;
    float4 v = ((const float4*)out)[i];
    v.x = fmaxf(v.x * sc[c4 + 0] + sh[c4 + 0], 0.f);
    v.y = fmaxf(v.y * sc[c4 + 1] + sh[c4 + 1], 0.f);
    v.z = fmaxf(v.z * sc[c4 + 2] + sh[c4 + 2], 0.f);
    v.w = fmaxf(v.w * sc[c4 + 3] + sh[c4 + 3], 0.f);
    ((float4*)out)[i] = v;
}

extern "C" void kernel_launch(void* const* d_in, const int* in_sizes, int n_in,
                              void* d_out, int out_size, void* d_ws, size_t ws_size,
                              hipStream_t stream) {
    const float* x      = (const float*)d_in[0];
    const int*   ei     = (const int*)d_in[1];   // [2][N_EDGES]
    const float* weight = (const float*)d_in[2];
    const float* bias   = (const float*)d_in[3];
    const float* gamma  = (const float*)d_in[4];
    const float* beta   = (const float*)d_in[5];

    float*          xs       = (float*)((char*)d_ws + XS_OFF);
    int*            degi     = (int*)  ((char*)d_ws + DEG_OFF);
    float*          dinv     = (float*)((char*)d_ws + DEG_OFF);   // overwrites degi after scans
    int*            rowstart = (int*)  ((char*)d_ws + ROW_OFF);
    int*            srcs     = (int*)  ((char*)d_ws + SRC_OFF);
    float*          sums     = (float*)((char*)d_ws + SUM_OFF);
    int*            bsum     = (int*)  ((char*)d_ws + BS_OFF);
    int*            boff     = bsum + SCB;
    unsigned short* wt_hi    = (unsigned short*)((char*)d_ws + WT_OFF);
    unsigned short* wt_lo    = wt_hi + C * C;

    hipMemsetAsync((char*)d_ws + DEG_OFF, 0, DEG_BYTES, stream);
    hipMemsetAsync((char*)d_ws + SUM_OFF, 0, SUM_BYTES, stream);

    // 0) W -> W^T bf16 hi/lo (independent)
    wconv_kernel<<<(C * C) / 256, 256, 0, stream>>>(weight, wt_hi, wt_lo);
    // 1) dst-degree histogram
    deg_kernel<<<(N_EDGES + 255) / 256, 256, 0, stream>>>(ei, degi);
    // 2) parallel exclusive scan -> rowstart
    scanA_kernel<<<SCB, 256, 0, stream>>>(degi, bsum);
    scanB_kernel<<<1, 256, 0, stream>>>(bsum, boff);
    scanC_kernel<<<SCB, 256, 0, stream>>>(degi, boff, rowstart);
    // 3) dinv = rsqrt(deg+1) (overwrites degi — after scans read it)
    dinv_kernel<<<(N_NODES + 255) / 256, 256, 0, stream>>>(degi, dinv);
    // 4) CSR fill: srcs sorted by dst (rowstart becomes row-end cursors)
    fill_kernel<<<(N_EDGES + 255) / 256, 256, 0, stream>>>(ei, rowstart, srcs);
    // 5) xs = (x @ W) * dinv[row]  (bf16-split MFMA)
    xw_mfma_kernel<<<(N_NODES + 63) / 64, 256, 0, stream>>>(x, wt_hi, wt_lo, dinv, xs);
    // 6) segmented gather-reduce + self-loop + scale + bias + BN partials -> out
    gather_kernel<<<GB, 256, 0, stream>>>(srcs, rowstart, xs, dinv, bias,
                                          (float*)d_out, sums);
    // 7) BN normalize + ReLU
    finalize_kernel<<<(N_NODES * (C / 4)) / 256, 256, 0, stream>>>(sums, gamma, beta,
                                                                   (float*)d_out);
}